// Round 24
// baseline (94.866 us; speedup 1.0000x reference)
//
#include <hip/hip_runtime.h>
#include <hip/hip_bf16.h>

#define BATCH 32
#define CIN   256
#define COUT  256
#define Hd    56
#define Wd    56
#define HW    (Hd*Wd)

typedef __attribute__((ext_vector_type(8))) short bf16x8;
typedef __attribute__((ext_vector_type(4))) short bf16x4;
typedef __attribute__((ext_vector_type(4))) float f32x4;

__device__ __forceinline__ unsigned short f2bf_rne(float f) {
    unsigned u = __builtin_bit_cast(unsigned, f);
    u += 0x7fffu + ((u >> 16) & 1u);
    return (unsigned short)(u >> 16);
}

// ---------------------------------------------------------------------------
// Weight prep + bsum (R20-R23-verified): blocks [0,48) wprep, [48,80) bsum.
// Lane-linear 1 KB chunks, residue-interleaved: ic = (p*16+jj)*4+rr.
// ---------------------------------------------------------------------------
__global__ __launch_bounds__(512) void hetconv_wprep(const float* __restrict__ W,
                                                     const float* __restrict__ bb_,
                                                     unsigned short* __restrict__ Wc3,
                                                     unsigned short* __restrict__ Wg3,
                                                     float* __restrict__ bsum) {
    const int bid = blockIdx.x;
    const int tid = threadIdx.x;
    const int lane = tid & 63;
    const int wid  = tid >> 6;

    if (bid < 48) {                      // ---- wprep: 8 chunks per block ----
        const int u = bid * 8 + wid;     // [0,384)
        const int l15 = lane & 15;
        const int l4  = lane >> 4;
        if (u < 128) {                   // Wc: u = r*32+p*8+ks*4+mf
            const int mf = u & 3;
            const int ks = (u >> 2) & 1;
            const int p  = (u >> 3) & 3;
            const int r  = u >> 5;
            const int np = r * 64 + mf * 16 + l15;
            const int n  = ((np & 63) << 2) | r;
            #pragma unroll
            for (int e = 0; e < 8; ++e) {
                int kq = ks * 32 + l4 * 8 + e;
                int rr = kq >> 4, jj = kq & 15;
                int ic = (p * 16 + jj) * 4 + rr;
                Wc3[u * 512 + lane * 8 + e] = f2bf_rne(W[(n * CIN + ic) * 9 + 4]);
            }
        } else {                         // Wg: u2 = r*64+p*16+tp*4+mf
            const int u2 = u - 128;
            const int mf = u2 & 3;
            const int tp = (u2 >> 2) & 3;
            const int p  = (u2 >> 4) & 3;
            const int r  = u2 >> 6;
            const int np = r * 64 + mf * 16 + l15;
            const int n  = ((np & 63) << 2) | r;
            const int t8  = tp * 2 + (l4 >> 1);
            const int tap = t8 + (t8 >= 4);
            #pragma unroll
            for (int e = 0; e < 8; ++e) {
                int jj = (l4 & 1) * 8 + e;
                int ic = (p * 16 + jj) * 4 + r;
                Wg3[u2 * 512 + lane * 8 + e] = f2bf_rne(W[(n * CIN + ic) * 9 + tap]);
            }
        }
    } else {                             // ---- bsum: 8 np per block ----
        const int np = (bid - 48) * 8 + wid;     // [0,256)
        const int n = ((np & 63) << 2) | (np >> 6);
        float s = 0.f;
        for (int i = lane; i < CIN; i += 64) s += bb_[n * CIN + i];
        #pragma unroll
        for (int off = 32; off > 0; off >>= 1) s += __shfl_down(s, off, 64);
        if (lane == 0) bsum[np] = s;
    }
}

// ---------------------------------------------------------------------------
// Fused main (R23 + 1-deep CONVERT/COMPUTE pipeline): 896 blocks
// (XCD-swizzled) x 1024 threads = 16 waves = (h, mh, r); per-wave 32 out-ch
// x 64 cols, acc[2][4] = 32 AGPR.  Each slab's conversion is spread over
// ALL 1024 threads (hf = tid>>9 thread-constant) -> 4 loads + 4 x 8B writes
// per thread per slab (16 VGPRs live).  Pipeline: CONV(0) | sync |
// {CONV(p+1) || COMP(p)} x3 | sync | COMP(3) — every CONVERT after the
// first hides under a COMPUTE via 16-wave drift.  Compute + epilogue
// verbatim R19-R23.
// ---------------------------------------------------------------------------
__global__ __launch_bounds__(1024, 2) void hetconv_main(const float* __restrict__ x,
                             const unsigned short* __restrict__ Wc3,
                             const unsigned short* __restrict__ Wg3,
                             const float* __restrict__ bsum,
                             float* __restrict__ y) {
    __shared__ unsigned short xs[4][16384];   // 4 x 32 KB slabs (epilogue reuses 0-1)

    const int bid  = blockIdx.x;
    const int work = (bid & 7) * 112 + (bid >> 3);   // XCD-contiguous (896 = 8*112)
    const int b    = work / 28;
    const int R0   = (work % 28) * 2;
    const int tid = threadIdx.x;
    const int lane = tid & 63;
    const int wid  = tid >> 6;        // [0,16)
    const int h  = wid & 1;
    const int mh = (wid >> 1) & 1;
    const int r  = wid >> 2;
    const int l15 = lane & 15;
    const int l4  = lane >> 4;

    const float* xbase = x + (size_t)b * CIN * HW;

    f32x4 acc[2][4];
    #pragma unroll
    for (int i = 0; i < 2; ++i)
        #pragma unroll
        for (int j = 0; j < 4; ++j) acc[i][j] = f32x4{0.f, 0.f, 0.f, 0.f};

    // ---- conversion: full slab covered by 1024 threads; lane address
    // fields [hf1|row2|ol2(+oh1)|q4]; per thread 4 loads + 4 x 8B writes.
    const int cq   = tid & 15;                        // col quad; 14,15 -> zeros
    const int coct = ((tid >> 4) & 3) | (((tid >> 6) & 1) << 2);
    const int crow = (tid >> 7) & 3;                  // slab-local row
    const int chf  = tid >> 9;                        // channel half (constant)
    const int cgrow = R0 - 1 + crow;
    const bool cok = (cgrow >= 0) && (cgrow < Hd) && (cq < 14);
    const float* cxrow = xbase + (size_t)cgrow * Wd + cq * 4;

    auto CONVERT = [&](int pass, unsigned short* dst) {
        f32x4 v[4];
        #pragma unroll
        for (int e4 = 0; e4 < 4; ++e4) {
            int kq = coct * 8 + chf * 4 + e4;
            int rr = kq >> 4, jj = kq & 15;
            int ic = (pass * 16 + jj) * 4 + rr;
            v[e4] = cok ? *reinterpret_cast<const f32x4*>(cxrow + (size_t)ic * HW)
                        : f32x4{0.f, 0.f, 0.f, 0.f};
        }
        #pragma unroll
        for (int i = 0; i < 4; ++i) {
            int col = cq * 4 + i;
            bf16x4 pk;
            #pragma unroll
            for (int e4 = 0; e4 < 4; ++e4) pk[e4] = (short)f2bf_rne(v[e4][i]);
            *reinterpret_cast<bf16x4*>(
                reinterpret_cast<char*>(dst) + (crow * 64 + col) * 128
                + ((coct ^ (col & 7)) << 4) + chf * 8) = pk;
        }
    };

    // ---- compute one pass (verbatim) ----
    auto COMPUTE = [&](int p) {
        const unsigned short* buf = xs[p];
        const int srow = (h + 1) * 64;
        #pragma unroll
        for (int ks = 0; ks < 2; ++ks) {
            bf16x8 a[2];
            #pragma unroll
            for (int mfl = 0; mfl < 2; ++mfl) {
                int chunk = r * 32 + p * 8 + ks * 4 + mh * 2 + mfl;
                a[mfl] = *reinterpret_cast<const bf16x8*>(
                    Wc3 + ((size_t)chunk << 9) + lane * 8);
            }
            #pragma unroll
            for (int nf = 0; nf < 4; ++nf) {
                int col = nf * 16 + l15;
                int pix = srow + col;
                int oct = ks * 4 + l4;
                int addr = pix * 128 + ((oct ^ (col & 7)) << 4);
                bf16x8 bbv = *reinterpret_cast<const bf16x8*>(
                    reinterpret_cast<const char*>(buf) + addr);
                #pragma unroll
                for (int mfl = 0; mfl < 2; ++mfl)
                    acc[mfl][nf] = __builtin_amdgcn_mfma_f32_16x16x32_bf16(
                        a[mfl], bbv, acc[mfl][nf], 0, 0, 0);
            }
        }
        #pragma unroll
        for (int tp = 0; tp < 4; ++tp) {
            const int t8  = tp * 2 + (l4 >> 1);
            const int tap = t8 + (t8 >= 4);
            const int dy  = tap / 3 - 1;
            const int dx  = tap % 3 - 1;
            const int lr  = h + 1 + dy;
            const int oct = r * 2 + (l4 & 1);
            bf16x8 ag[2];
            #pragma unroll
            for (int mfl = 0; mfl < 2; ++mfl) {
                int chunk = r * 64 + p * 16 + tp * 4 + mh * 2 + mfl;
                ag[mfl] = *reinterpret_cast<const bf16x8*>(
                    Wg3 + ((size_t)chunk << 9) + lane * 8);
            }
            #pragma unroll
            for (int nf = 0; nf < 4; ++nf) {
                int c2 = nf * 16 + l15 + dx;
                c2 = ((unsigned)c2 < 64u) ? c2 : 56;   // col 56 is zero pad
                int pix  = lr * 64 + c2;
                int addr = pix * 128 + ((oct ^ (c2 & 7)) << 4);
                bf16x8 bbv = *reinterpret_cast<const bf16x8*>(
                    reinterpret_cast<const char*>(buf) + addr);
                #pragma unroll
                for (int mfl = 0; mfl < 2; ++mfl)
                    acc[mfl][nf] = __builtin_amdgcn_mfma_f32_16x16x32_bf16(
                        ag[mfl], bbv, acc[mfl][nf], 0, 0, 0);
            }
        }
    };

    // ---- 1-deep pipeline ----
    CONVERT(0, xs[0]);
    __syncthreads();
    CONVERT(1, xs[1]);  COMPUTE(0);
    __syncthreads();
    CONVERT(2, xs[2]);  COMPUTE(1);
    __syncthreads();
    CONVERT(3, xs[3]);  COMPUTE(2);
    __syncthreads();
    COMPUTE(3);
    __syncthreads();                      // slab reads done; xs reusable

    // ---- epilogue (verbatim): 2 rounds via xs scratch ----
    float* lf = reinterpret_cast<float*>(xs[0]);     // 59,392 B <= 2 slabs
    #pragma unroll
    for (int q = 0; q < 2; ++q) {
        if ((r >> 1) == q) {
            #pragma unroll
            for (int mfl = 0; mfl < 2; ++mfl) {
                #pragma unroll
                for (int j = 0; j < 4; ++j) {
                    int chL = (r & 1) * 64 + mh * 32 + mfl * 16 + l4 * 4 + j;
                    float bias = bsum[q * 128 + chL];
                    #pragma unroll
                    for (int nf = 0; nf < 4; ++nf) {
                        int col = nf * 16 + l15;
                        if (col < Wd)
                            lf[chL * 116 + h * 56 + col] = acc[mfl][nf][j] + bias;
                    }
                }
            }
        }
        __syncthreads();
        #pragma unroll
        for (int it = 0; it < 4; ++it) {
            int v = it * 1024 + tid;           // 128 chL x 28 float4
            if (v < 3584) {
                int chL = v / 28;
                int f   = v % 28;
                int h2  = (f >= 14) ? 1 : 0;
                int colS = (f - h2 * 14) * 4;
                int n = ((chL & 63) << 2) | (q * 2 + (chL >> 6));
                f32x4 val = *reinterpret_cast<const f32x4*>(lf + chL * 116 + f * 4);
                __builtin_nontemporal_store(val, reinterpret_cast<f32x4*>(
                    y + (((size_t)b * COUT + n) * Hd + (R0 + h2)) * Wd + colS));
            }
        }
        __syncthreads();
    }
}

extern "C" void kernel_launch(void* const* d_in, const int* in_sizes, int n_in,
                              void* d_out, int out_size, void* d_ws, size_t ws_size,
                              hipStream_t stream) {
    const float* x = (const float*)d_in[0];
    const float* W = (const float*)d_in[1];
    const float* b = (const float*)d_in[2];
    float* y = (float*)d_out;

    unsigned short* Wc3  = (unsigned short*)d_ws;                        // 131072 B
    unsigned short* Wg3  = (unsigned short*)((char*)d_ws + 131072);      // 262144 B
    float*          bsum = (float*)((char*)d_ws + 393216);               // 1024 B

    hipLaunchKernelGGL(hetconv_wprep, dim3(80), dim3(512), 0, stream,
                       W, b, Wc3, Wg3, bsum);
    hipLaunchKernelGGL(hetconv_main, dim3(BATCH * 28), dim3(1024), 0, stream,
                       x, Wc3, Wg3, bsum, y);
}

// Round 25
// 87.822 us; speedup vs baseline: 1.0802x; 1.0802x over previous
//
#include <hip/hip_runtime.h>
#include <hip/hip_bf16.h>

#define BATCH 32
#define CIN   256
#define COUT  256
#define Hd    56
#define Wd    56
#define HW    (Hd*Wd)

typedef __attribute__((ext_vector_type(8))) short bf16x8;
typedef __attribute__((ext_vector_type(4))) short bf16x4;
typedef __attribute__((ext_vector_type(4))) float f32x4;

__device__ __forceinline__ unsigned short f2bf_rne(float f) {
    unsigned u = __builtin_bit_cast(unsigned, f);
    u += 0x7fffu + ((u >> 16) & 1u);
    return (unsigned short)(u >> 16);
}

// ---------------------------------------------------------------------------
// Weight prep + bsum (R20-R23-verified): blocks [0,48) wprep, [48,80) bsum.
// Lane-linear 1 KB chunks, residue-interleaved: ic = (p*16+jj)*4+rr.
// ---------------------------------------------------------------------------
__global__ __launch_bounds__(512) void hetconv_wprep(const float* __restrict__ W,
                                                     const float* __restrict__ bb_,
                                                     unsigned short* __restrict__ Wc3,
                                                     unsigned short* __restrict__ Wg3,
                                                     float* __restrict__ bsum) {
    const int bid = blockIdx.x;
    const int tid = threadIdx.x;
    const int lane = tid & 63;
    const int wid  = tid >> 6;

    if (bid < 48) {                      // ---- wprep: 8 chunks per block ----
        const int u = bid * 8 + wid;     // [0,384)
        const int l15 = lane & 15;
        const int l4  = lane >> 4;
        if (u < 128) {                   // Wc: u = r*32+p*8+ks*4+mf
            const int mf = u & 3;
            const int ks = (u >> 2) & 1;
            const int p  = (u >> 3) & 3;
            const int r  = u >> 5;
            const int np = r * 64 + mf * 16 + l15;
            const int n  = ((np & 63) << 2) | r;
            #pragma unroll
            for (int e = 0; e < 8; ++e) {
                int kq = ks * 32 + l4 * 8 + e;
                int rr = kq >> 4, jj = kq & 15;
                int ic = (p * 16 + jj) * 4 + rr;
                Wc3[u * 512 + lane * 8 + e] = f2bf_rne(W[(n * CIN + ic) * 9 + 4]);
            }
        } else {                         // Wg: u2 = r*64+p*16+tp*4+mf
            const int u2 = u - 128;
            const int mf = u2 & 3;
            const int tp = (u2 >> 2) & 3;
            const int p  = (u2 >> 4) & 3;
            const int r  = u2 >> 6;
            const int np = r * 64 + mf * 16 + l15;
            const int n  = ((np & 63) << 2) | r;
            const int t8  = tp * 2 + (l4 >> 1);
            const int tap = t8 + (t8 >= 4);
            #pragma unroll
            for (int e = 0; e < 8; ++e) {
                int jj = (l4 & 1) * 8 + e;
                int ic = (p * 16 + jj) * 4 + r;
                Wg3[u2 * 512 + lane * 8 + e] = f2bf_rne(W[(n * CIN + ic) * 9 + tap]);
            }
        }
    } else {                             // ---- bsum: 8 np per block ----
        const int np = (bid - 48) * 8 + wid;     // [0,256)
        const int n = ((np & 63) << 2) | (np >> 6);
        float s = 0.f;
        for (int i = lane; i < CIN; i += 64) s += bb_[n * CIN + i];
        #pragma unroll
        for (int off = 32; off > 0; off >>= 1) s += __shfl_down(s, off, 64);
        if (lane == 0) bsum[np] = s;
    }
}

// ---------------------------------------------------------------------------
// Fused main (R23 schedule + single-round epilogue): 896 blocks
// (XCD-swizzled) x 1024 threads = 16 waves = (h, mh, r); per-wave 32 out-ch
// x 64 cols, acc[2][4] = 32 AGPR.  CONVERT covers a slab with 512 threads
// (wave-half hb), two SERIAL halves of 4 channels (unroll 1 -> 16 VGPRs of
// x-data live; R23's spill fix).  Schedule: CONV(0,1) | sync | COMP(0) |
// CONV(2,3) | COMP(1) | sync | COMP(2) | COMP(3) | sync | epilogue.
// Epilogue: ONE round — all 256 channels into the full 128 KB xs scratch
// (256 x 116 floats = 118.8 KB), one sync, 7 predicate-free f32x4
// stores/thread (was 2 rounds x 2 syncs).
// ---------------------------------------------------------------------------
__global__ __launch_bounds__(1024, 2) void hetconv_main(const float* __restrict__ x,
                             const unsigned short* __restrict__ Wc3,
                             const unsigned short* __restrict__ Wg3,
                             const float* __restrict__ bsum,
                             float* __restrict__ y) {
    __shared__ unsigned short xs[4][16384];   // 4 x 32 KB slabs (epilogue uses all)

    const int bid  = blockIdx.x;
    const int work = (bid & 7) * 112 + (bid >> 3);   // XCD-contiguous (896 = 8*112)
    const int b    = work / 28;
    const int R0   = (work % 28) * 2;
    const int tid = threadIdx.x;
    const int lane = tid & 63;
    const int wid  = tid >> 6;        // [0,16)
    const int h  = wid & 1;
    const int mh = (wid >> 1) & 1;
    const int r  = wid >> 2;
    const int l15 = lane & 15;
    const int l4  = lane >> 4;

    const float* xbase = x + (size_t)b * CIN * HW;

    f32x4 acc[2][4];
    #pragma unroll
    for (int i = 0; i < 2; ++i)
        #pragma unroll
        for (int j = 0; j < 4; ++j) acc[i][j] = f32x4{0.f, 0.f, 0.f, 0.f};

    // ---- conversion (R23-verified): 512-assignment cover per pass;
    // lane = [row2|ol2|q4]; two SERIAL halves of 4 channels.
    auto CONVERT = [&](int pass, unsigned short* dst) {
        const int a   = tid & 511;
        const int q   = a & 15;                       // col quad; 14,15 -> zeros
        const int oct = ((a >> 4) & 3) | (((a >> 6) & 1) << 2);
        const int row = (a >> 7) & 3;                 // slab-local row
        const int grow = R0 - 1 + row;
        const bool ok = (grow >= 0) && (grow < Hd) && (q < 14);
        const float* xrow = xbase + (size_t)grow * Wd + q * 4;
        #pragma unroll 1
        for (int hf = 0; hf < 2; ++hf) {
            f32x4 v[4];
            #pragma unroll
            for (int e4 = 0; e4 < 4; ++e4) {
                int kq = oct * 8 + hf * 4 + e4;
                int rr = kq >> 4, jj = kq & 15;
                int ic = (pass * 16 + jj) * 4 + rr;
                v[e4] = ok ? *reinterpret_cast<const f32x4*>(xrow + (size_t)ic * HW)
                           : f32x4{0.f, 0.f, 0.f, 0.f};
            }
            #pragma unroll
            for (int i = 0; i < 4; ++i) {
                int col = q * 4 + i;
                bf16x4 pk;
                #pragma unroll
                for (int e4 = 0; e4 < 4; ++e4) pk[e4] = (short)f2bf_rne(v[e4][i]);
                *reinterpret_cast<bf16x4*>(
                    reinterpret_cast<char*>(dst) + (row * 64 + col) * 128
                    + ((oct ^ (col & 7)) << 4) + hf * 8) = pk;
            }
        }
    };

    // ---- compute one pass (verbatim R19-R23) ----
    auto COMPUTE = [&](int p) {
        const unsigned short* buf = xs[p];
        const int srow = (h + 1) * 64;
        #pragma unroll
        for (int ks = 0; ks < 2; ++ks) {
            bf16x8 a[2];
            #pragma unroll
            for (int mfl = 0; mfl < 2; ++mfl) {
                int chunk = r * 32 + p * 8 + ks * 4 + mh * 2 + mfl;
                a[mfl] = *reinterpret_cast<const bf16x8*>(
                    Wc3 + ((size_t)chunk << 9) + lane * 8);
            }
            #pragma unroll
            for (int nf = 0; nf < 4; ++nf) {
                int col = nf * 16 + l15;
                int pix = srow + col;
                int oct = ks * 4 + l4;
                int addr = pix * 128 + ((oct ^ (col & 7)) << 4);
                bf16x8 bbv = *reinterpret_cast<const bf16x8*>(
                    reinterpret_cast<const char*>(buf) + addr);
                #pragma unroll
                for (int mfl = 0; mfl < 2; ++mfl)
                    acc[mfl][nf] = __builtin_amdgcn_mfma_f32_16x16x32_bf16(
                        a[mfl], bbv, acc[mfl][nf], 0, 0, 0);
            }
        }
        #pragma unroll
        for (int tp = 0; tp < 4; ++tp) {
            const int t8  = tp * 2 + (l4 >> 1);
            const int tap = t8 + (t8 >= 4);
            const int dy  = tap / 3 - 1;
            const int dx  = tap % 3 - 1;
            const int lr  = h + 1 + dy;
            const int oct = r * 2 + (l4 & 1);
            bf16x8 ag[2];
            #pragma unroll
            for (int mfl = 0; mfl < 2; ++mfl) {
                int chunk = r * 64 + p * 16 + tp * 4 + mh * 2 + mfl;
                ag[mfl] = *reinterpret_cast<const bf16x8*>(
                    Wg3 + ((size_t)chunk << 9) + lane * 8);
            }
            #pragma unroll
            for (int nf = 0; nf < 4; ++nf) {
                int c2 = nf * 16 + l15 + dx;
                c2 = ((unsigned)c2 < 64u) ? c2 : 56;   // col 56 is zero pad
                int pix  = lr * 64 + c2;
                int addr = pix * 128 + ((oct ^ (c2 & 7)) << 4);
                bf16x8 bbv = *reinterpret_cast<const bf16x8*>(
                    reinterpret_cast<const char*>(buf) + addr);
                #pragma unroll
                for (int mfl = 0; mfl < 2; ++mfl)
                    acc[mfl][nf] = __builtin_amdgcn_mfma_f32_16x16x32_bf16(
                        ag[mfl], bbv, acc[mfl][nf], 0, 0, 0);
            }
        }
    };

    // ---- schedule (R23-proven) ----
    const int hb = tid >> 9;              // wave-half: 0 or 1
    CONVERT(hb, xs[hb]);                  // phase A: slabs 0,1
    __syncthreads();
    COMPUTE(0);
    CONVERT(2 + hb, xs[2 + hb]);          // phase B: slabs 2,3 (no barrier yet)
    COMPUTE(1);
    __syncthreads();                      // slabs 2,3 ready
    COMPUTE(2);
    COMPUTE(3);
    __syncthreads();                      // slab reads done; xs reusable

    // ---- epilogue: SINGLE round — 256 ch x 116 floats in full xs scratch ----
    float* lf = reinterpret_cast<float*>(xs[0]);     // 118,784 B <= 128 KB
    {
        #pragma unroll
        for (int mfl = 0; mfl < 2; ++mfl) {
            #pragma unroll
            for (int j = 0; j < 4; ++j) {
                int np = r * 64 + mh * 32 + mfl * 16 + l4 * 4 + j;   // [0,256)
                float bias = bsum[np];
                #pragma unroll
                for (int nf = 0; nf < 4; ++nf) {
                    int col = nf * 16 + l15;
                    if (col < Wd)
                        lf[np * 116 + h * 56 + col] = acc[mfl][nf][j] + bias;
                }
            }
        }
    }
    __syncthreads();
    #pragma unroll
    for (int it = 0; it < 7; ++it) {
        int v = it * 1024 + tid;               // 256 chL x 28 float4, exact
        int chL = v / 28;
        int f   = v % 28;
        int h2  = (f >= 14) ? 1 : 0;
        int colS = (f - h2 * 14) * 4;
        int n = ((chL & 63) << 2) | (chL >> 6);
        f32x4 val = *reinterpret_cast<const f32x4*>(lf + chL * 116 + f * 4);
        __builtin_nontemporal_store(val, reinterpret_cast<f32x4*>(
            y + (((size_t)b * COUT + n) * Hd + (R0 + h2)) * Wd + colS));
    }
}

extern "C" void kernel_launch(void* const* d_in, const int* in_sizes, int n_in,
                              void* d_out, int out_size, void* d_ws, size_t ws_size,
                              hipStream_t stream) {
    const float* x = (const float*)d_in[0];
    const float* W = (const float*)d_in[1];
    const float* b = (const float*)d_in[2];
    float* y = (float*)d_out;

    unsigned short* Wc3  = (unsigned short*)d_ws;                        // 131072 B
    unsigned short* Wg3  = (unsigned short*)((char*)d_ws + 131072);      // 262144 B
    float*          bsum = (float*)((char*)d_ws + 393216);               // 1024 B

    hipLaunchKernelGGL(hetconv_wprep, dim3(80), dim3(512), 0, stream,
                       W, b, Wc3, Wg3, bsum);
    hipLaunchKernelGGL(hetconv_main, dim3(BATCH * 28), dim3(1024), 0, stream,
                       x, Wc3, Wg3, bsum, y);
}

// Round 26
// 87.530 us; speedup vs baseline: 1.0838x; 1.0033x over previous
//
#include <hip/hip_runtime.h>
#include <hip/hip_bf16.h>

#define BATCH 32
#define CIN   256
#define COUT  256
#define Hd    56
#define Wd    56
#define HW    (Hd*Wd)

typedef __attribute__((ext_vector_type(8))) short bf16x8;
typedef __attribute__((ext_vector_type(4))) short bf16x4;
typedef __attribute__((ext_vector_type(4))) float f32x4;

__device__ __forceinline__ unsigned short f2bf_rne(float f) {
    unsigned u = __builtin_bit_cast(unsigned, f);
    u += 0x7fffu + ((u >> 16) & 1u);
    return (unsigned short)(u >> 16);
}

// native cast — lets the compiler pattern-match v_cvt_pk_bf16_f32 pairs
__device__ __forceinline__ short f2bf_hw(float f) {
    return (short)__builtin_bit_cast(unsigned short, (__bf16)f);
}

// ---------------------------------------------------------------------------
// Weight prep + bsum (R20-R25-verified, unchanged): blocks [0,48) wprep,
// [48,80) bsum.  Lane-linear 1 KB chunks, residue-interleaved:
// ic = (p*16+jj)*4+rr.
// ---------------------------------------------------------------------------
__global__ __launch_bounds__(512) void hetconv_wprep(const float* __restrict__ W,
                                                     const float* __restrict__ bb_,
                                                     unsigned short* __restrict__ Wc3,
                                                     unsigned short* __restrict__ Wg3,
                                                     float* __restrict__ bsum) {
    const int bid = blockIdx.x;
    const int tid = threadIdx.x;
    const int lane = tid & 63;
    const int wid  = tid >> 6;

    if (bid < 48) {                      // ---- wprep: 8 chunks per block ----
        const int u = bid * 8 + wid;     // [0,384)
        const int l15 = lane & 15;
        const int l4  = lane >> 4;
        if (u < 128) {                   // Wc: u = r*32+p*8+ks*4+mf
            const int mf = u & 3;
            const int ks = (u >> 2) & 1;
            const int p  = (u >> 3) & 3;
            const int r  = u >> 5;
            const int np = r * 64 + mf * 16 + l15;
            const int n  = ((np & 63) << 2) | r;
            #pragma unroll
            for (int e = 0; e < 8; ++e) {
                int kq = ks * 32 + l4 * 8 + e;
                int rr = kq >> 4, jj = kq & 15;
                int ic = (p * 16 + jj) * 4 + rr;
                Wc3[u * 512 + lane * 8 + e] = f2bf_rne(W[(n * CIN + ic) * 9 + 4]);
            }
        } else {                         // Wg: u2 = r*64+p*16+tp*4+mf
            const int u2 = u - 128;
            const int mf = u2 & 3;
            const int tp = (u2 >> 2) & 3;
            const int p  = (u2 >> 4) & 3;
            const int r  = u2 >> 6;
            const int np = r * 64 + mf * 16 + l15;
            const int n  = ((np & 63) << 2) | r;
            const int t8  = tp * 2 + (l4 >> 1);
            const int tap = t8 + (t8 >= 4);
            #pragma unroll
            for (int e = 0; e < 8; ++e) {
                int jj = (l4 & 1) * 8 + e;
                int ic = (p * 16 + jj) * 4 + r;
                Wg3[u2 * 512 + lane * 8 + e] = f2bf_rne(W[(n * CIN + ic) * 9 + tap]);
            }
        }
    } else {                             // ---- bsum: 8 np per block ----
        const int np = (bid - 48) * 8 + wid;     // [0,256)
        const int n = ((np & 63) << 2) | (np >> 6);
        float s = 0.f;
        for (int i = lane; i < CIN; i += 64) s += bb_[n * CIN + i];
        #pragma unroll
        for (int off = 32; off > 0; off >>= 1) s += __shfl_down(s, off, 64);
        if (lane == 0) bsum[np] = s;
    }
}

// ---------------------------------------------------------------------------
// Fused main (R25 structure; CONVERT pack now native __bf16 casts so the
// compiler emits v_cvt_pk_bf16_f32 — 3x less conversion VALU): 896 blocks
// (XCD-swizzled) x 1024 threads = 16 waves = (h, mh, r); per-wave 32 out-ch
// x 64 cols, acc[2][4] = 32 AGPR.  Schedule: CONV(0,1) | sync | COMP(0) |
// CONV(2,3) | COMP(1) | sync | COMP(2) | COMP(3) | sync | 1-round epilogue.
// ---------------------------------------------------------------------------
__global__ __launch_bounds__(1024, 2) void hetconv_main(const float* __restrict__ x,
                             const unsigned short* __restrict__ Wc3,
                             const unsigned short* __restrict__ Wg3,
                             const float* __restrict__ bsum,
                             float* __restrict__ y) {
    __shared__ unsigned short xs[4][16384];   // 4 x 32 KB slabs (epilogue uses all)

    const int bid  = blockIdx.x;
    const int work = (bid & 7) * 112 + (bid >> 3);   // XCD-contiguous (896 = 8*112)
    const int b    = work / 28;
    const int R0   = (work % 28) * 2;
    const int tid = threadIdx.x;
    const int lane = tid & 63;
    const int wid  = tid >> 6;        // [0,16)
    const int h  = wid & 1;
    const int mh = (wid >> 1) & 1;
    const int r  = wid >> 2;
    const int l15 = lane & 15;
    const int l4  = lane >> 4;

    const float* xbase = x + (size_t)b * CIN * HW;

    f32x4 acc[2][4];
    #pragma unroll
    for (int i = 0; i < 2; ++i)
        #pragma unroll
        for (int j = 0; j < 4; ++j) acc[i][j] = f32x4{0.f, 0.f, 0.f, 0.f};

    // ---- conversion (R23 cover, native-cast pack): 512-assignment cover
    // per pass; lane = [row2|ol2|q4]; two SERIAL halves of 4 channels.
    auto CONVERT = [&](int pass, unsigned short* dst) {
        const int a   = tid & 511;
        const int q   = a & 15;                       // col quad; 14,15 -> zeros
        const int oct = ((a >> 4) & 3) | (((a >> 6) & 1) << 2);
        const int row = (a >> 7) & 3;                 // slab-local row
        const int grow = R0 - 1 + row;
        const bool ok = (grow >= 0) && (grow < Hd) && (q < 14);
        const float* xrow = xbase + (size_t)grow * Wd + q * 4;
        #pragma unroll 1
        for (int hf = 0; hf < 2; ++hf) {
            f32x4 v[4];
            #pragma unroll
            for (int e4 = 0; e4 < 4; ++e4) {
                int kq = oct * 8 + hf * 4 + e4;
                int rr = kq >> 4, jj = kq & 15;
                int ic = (pass * 16 + jj) * 4 + rr;
                v[e4] = ok ? *reinterpret_cast<const f32x4*>(xrow + (size_t)ic * HW)
                           : f32x4{0.f, 0.f, 0.f, 0.f};
            }
            #pragma unroll
            for (int i = 0; i < 4; ++i) {
                int col = q * 4 + i;
                bf16x4 pk;
                #pragma unroll
                for (int e4 = 0; e4 < 4; ++e4) pk[e4] = f2bf_hw(v[e4][i]);
                *reinterpret_cast<bf16x4*>(
                    reinterpret_cast<char*>(dst) + (row * 64 + col) * 128
                    + ((oct ^ (col & 7)) << 4) + hf * 8) = pk;
            }
        }
    };

    // ---- compute one pass (verbatim R19-R25) ----
    auto COMPUTE = [&](int p) {
        const unsigned short* buf = xs[p];
        const int srow = (h + 1) * 64;
        #pragma unroll
        for (int ks = 0; ks < 2; ++ks) {
            bf16x8 a[2];
            #pragma unroll
            for (int mfl = 0; mfl < 2; ++mfl) {
                int chunk = r * 32 + p * 8 + ks * 4 + mh * 2 + mfl;
                a[mfl] = *reinterpret_cast<const bf16x8*>(
                    Wc3 + ((size_t)chunk << 9) + lane * 8);
            }
            #pragma unroll
            for (int nf = 0; nf < 4; ++nf) {
                int col = nf * 16 + l15;
                int pix = srow + col;
                int oct = ks * 4 + l4;
                int addr = pix * 128 + ((oct ^ (col & 7)) << 4);
                bf16x8 bbv = *reinterpret_cast<const bf16x8*>(
                    reinterpret_cast<const char*>(buf) + addr);
                #pragma unroll
                for (int mfl = 0; mfl < 2; ++mfl)
                    acc[mfl][nf] = __builtin_amdgcn_mfma_f32_16x16x32_bf16(
                        a[mfl], bbv, acc[mfl][nf], 0, 0, 0);
            }
        }
        #pragma unroll
        for (int tp = 0; tp < 4; ++tp) {
            const int t8  = tp * 2 + (l4 >> 1);
            const int tap = t8 + (t8 >= 4);
            const int dy  = tap / 3 - 1;
            const int dx  = tap % 3 - 1;
            const int lr  = h + 1 + dy;
            const int oct = r * 2 + (l4 & 1);
            bf16x8 ag[2];
            #pragma unroll
            for (int mfl = 0; mfl < 2; ++mfl) {
                int chunk = r * 64 + p * 16 + tp * 4 + mh * 2 + mfl;
                ag[mfl] = *reinterpret_cast<const bf16x8*>(
                    Wg3 + ((size_t)chunk << 9) + lane * 8);
            }
            #pragma unroll
            for (int nf = 0; nf < 4; ++nf) {
                int c2 = nf * 16 + l15 + dx;
                c2 = ((unsigned)c2 < 64u) ? c2 : 56;   // col 56 is zero pad
                int pix  = lr * 64 + c2;
                int addr = pix * 128 + ((oct ^ (c2 & 7)) << 4);
                bf16x8 bbv = *reinterpret_cast<const bf16x8*>(
                    reinterpret_cast<const char*>(buf) + addr);
                #pragma unroll
                for (int mfl = 0; mfl < 2; ++mfl)
                    acc[mfl][nf] = __builtin_amdgcn_mfma_f32_16x16x32_bf16(
                        ag[mfl], bbv, acc[mfl][nf], 0, 0, 0);
            }
        }
    };

    // ---- schedule (R23-proven) ----
    const int hb = tid >> 9;              // wave-half: 0 or 1
    CONVERT(hb, xs[hb]);                  // phase A: slabs 0,1
    __syncthreads();
    COMPUTE(0);
    CONVERT(2 + hb, xs[2 + hb]);          // phase B: slabs 2,3 (no barrier yet)
    COMPUTE(1);
    __syncthreads();                      // slabs 2,3 ready
    COMPUTE(2);
    COMPUTE(3);
    __syncthreads();                      // slab reads done; xs reusable

    // ---- epilogue (R25): single round — 256 ch x 116 floats in xs scratch ----
    float* lf = reinterpret_cast<float*>(xs[0]);     // 118,784 B <= 128 KB
    {
        #pragma unroll
        for (int mfl = 0; mfl < 2; ++mfl) {
            #pragma unroll
            for (int j = 0; j < 4; ++j) {
                int np = r * 64 + mh * 32 + mfl * 16 + l4 * 4 + j;   // [0,256)
                float bias = bsum[np];
                #pragma unroll
                for (int nf = 0; nf < 4; ++nf) {
                    int col = nf * 16 + l15;
                    if (col < Wd)
                        lf[np * 116 + h * 56 + col] = acc[mfl][nf][j] + bias;
                }
            }
        }
    }
    __syncthreads();
    #pragma unroll
    for (int it = 0; it < 7; ++it) {
        int v = it * 1024 + tid;               // 256 chL x 28 float4, exact
        int chL = v / 28;
        int f   = v % 28;
        int h2  = (f >= 14) ? 1 : 0;
        int colS = (f - h2 * 14) * 4;
        int n = ((chL & 63) << 2) | (chL >> 6);
        f32x4 val = *reinterpret_cast<const f32x4*>(lf + chL * 116 + f * 4);
        __builtin_nontemporal_store(val, reinterpret_cast<f32x4*>(
            y + (((size_t)b * COUT + n) * Hd + (R0 + h2)) * Wd + colS));
    }
}

extern "C" void kernel_launch(void* const* d_in, const int* in_sizes, int n_in,
                              void* d_out, int out_size, void* d_ws, size_t ws_size,
                              hipStream_t stream) {
    const float* x = (const float*)d_in[0];
    const float* W = (const float*)d_in[1];
    const float* b = (const float*)d_in[2];
    float* y = (float*)d_out;

    unsigned short* Wc3  = (unsigned short*)d_ws;                        // 131072 B
    unsigned short* Wg3  = (unsigned short*)((char*)d_ws + 131072);      // 262144 B
    float*          bsum = (float*)((char*)d_ws + 393216);               // 1024 B

    hipLaunchKernelGGL(hetconv_wprep, dim3(80), dim3(512), 0, stream,
                       W, b, Wc3, Wg3, bsum);
    hipLaunchKernelGGL(hetconv_main, dim3(BATCH * 28), dim3(1024), 0, stream,
                       x, Wc3, Wg3, bsum, y);
}